// Round 4
// baseline (83.990 us; speedup 1.0000x reference)
//
#include <hip/hip_runtime.h>
#include <math.h>

#define HH 224
#define WW 224
#define NS 381                   // splats per image
#define BB 16                    // batch
#define TPB 128                  // 2 waves
#define TILE_W 32
#define TILE_H 32
#define TILES_X (WW / TILE_W)    // 7
#define BLKS_PER_IMG (TILES_X * (HH / TILE_H))  // 49
#define NBLK (BB * BLKS_PER_IMG)                // 784
#define NS_PAD 384
#define CUT 19.93f               // exp2 cutoff: weight < 2^-19.93 ~ 1e-6

// One fused kernel: per-tile cull+compact (computing per-splat constants on the
// fly from raw inputs) then render 8 px/thread (4 wide x 2 rows).
// Splat record (ONE float4): {ss, -px*ss, -py*ss, rgb as 10:10:10 unorm}
// where ss = sqrt(inv_two_var * log2(e)); weight = exp2(-((gx*ss-px*ss)^2 + (gy*ss-py*ss)^2)).
__global__ __launch_bounds__(TPB) void splat_render(const float* __restrict__ pos,
                                                    const float* __restrict__ col,
                                                    const float* __restrict__ siz,
                                                    float* __restrict__ out) {
    __shared__ float4 geo[NS_PAD];
    __shared__ int cnt;

    int blk = blockIdx.x;
    int b = blk / BLKS_PER_IMG;
    int t = blk - b * BLKS_PER_IMG;
    int tile_y = t / TILES_X;
    int tile_x = t - tile_y * TILES_X;

    if (threadIdx.x == 0) cnt = 0;
    __syncthreads();

    const float gstep = 2.0f / (float)(WW - 1);
    float x0 = -1.0f + (float)(tile_x * TILE_W) * gstep;
    float x1 = x0 + (float)(TILE_W - 1) * gstep;
    float y0 = -1.0f + (float)(tile_y * TILE_H) * gstep;
    float y1 = y0 + (float)(TILE_H - 1) * gstep;

    const float2* pb = (const float2*)(pos + (size_t)b * NS * 2);
    const float*  cb = col + (size_t)b * NS * 3;
    const float*  sb = siz + (size_t)b * NS;
    int lane = threadIdx.x & 63;

    // ---- cull + compact into LDS (3 rounds of 128) ----
    for (int r = 0; r < 3; ++r) {
        int i = threadIdx.x + r * TPB;
        bool pass = false;
        float4 A = make_float4(0.f, 0.f, 0.f, 0.f);
        if (i < NS) {
            float2 p = pb[i];
            float sg = sb[i] * (2.0f / (float)HH);
            float itv = 1.0f / (2.0f * sg * sg + 1e-8f);
            float ss = sqrtf(itv * 1.44269504088896340736f);
            float u = p.x * ss, v = p.y * ss;
            float dxm = fmaxf(fmaxf(x0 * ss - u, u - x1 * ss), 0.0f);
            float dym = fmaxf(fmaxf(y0 * ss - v, v - y1 * ss), 0.0f);
            pass = fmaf(dxm, dxm, dym * dym) < CUT;   // min scaled dist^2 to tile rect
            if (pass) {
                unsigned pr = (unsigned)fmaf(cb[3 * i + 0], 1023.0f, 0.5f);
                unsigned pg = (unsigned)fmaf(cb[3 * i + 1], 1023.0f, 0.5f);
                unsigned pc = (unsigned)fmaf(cb[3 * i + 2], 1023.0f, 0.5f);
                A = make_float4(ss, -u, -v, __uint_as_float(pr | (pg << 10) | (pc << 20)));
            }
        }
        unsigned long long mask = __ballot(pass);
        int ofs = __popcll(mask & ((1ull << lane) - 1ull));
        int tot = __popcll(mask);
        int base = 0;
        if (lane == 0 && tot) base = atomicAdd(&cnt, tot);
        base = __shfl(base, 0);
        if (pass) geo[base + ofs] = A;
    }
    __syncthreads();
    int m = cnt;
    int m4 = (m + 3) & ~3;      // pad to multiple of 4 with always-fail dummies
    if (threadIdx.x < (m4 - m))
        geo[m + threadIdx.x] = make_float4(0.f, 0.f, 1000.0f, 0.f);
    __syncthreads();
    m4 = __builtin_amdgcn_readfirstlane(m4);

    // ---- render 8 px/thread (4 wide x 2 rows) ----
    int tx = threadIdx.x & 7;           // 8 x-groups * 4 px = 32 px
    int ty = threadIdx.x >> 3;          // 16 thread-rows * 2 = 32 rows
    int w0 = tile_x * TILE_W + tx * 4;
    int h0 = tile_y * TILE_H + ty * 2;
    float gy0 = -1.0f + (float)h0 * gstep;
    float gy1 = gy0 + gstep;
    float gx0 = -1.0f + (float)w0 * gstep;
    float gx1 = gx0 + gstep;
    float gx2 = gx0 + 2.0f * gstep;
    float gx3 = gx0 + 3.0f * gstep;

    float r00 = 0.f, g00 = 0.f, b00 = 0.f, r01 = 0.f, g01 = 0.f, b01 = 0.f;
    float r02 = 0.f, g02 = 0.f, b02 = 0.f, r03 = 0.f, g03 = 0.f, b03 = 0.f;
    float r10 = 0.f, g10 = 0.f, b10 = 0.f, r11 = 0.f, g11 = 0.f, b11 = 0.f;
    float r12 = 0.f, g12 = 0.f, b12 = 0.f, r13 = 0.f, g13 = 0.f, b13 = 0.f;

#pragma unroll 4
    for (int j = 0; j < m4; ++j) {
        float4 A = geo[j];              // broadcast ds_read_b128
        float dy0 = fmaf(gy0, A.x, A.z);
        float dy1 = fmaf(gy1, A.x, A.z);
        float n0 = -(dy0 * dy0);
        float n1 = -(dy1 * dy1);
        if (fmaxf(n0, n1) > -CUT) {
            unsigned pk = __float_as_uint(A.w);
            const float q = (1.0f / 1023.0f);
            float cr = (float)(pk & 1023u) * q;
            float cg = (float)((pk >> 10) & 1023u) * q;
            float cc = (float)(pk >> 20) * q;
            float dx0 = fmaf(gx0, A.x, A.y);
            float dx1 = fmaf(gx1, A.x, A.y);
            float dx2 = fmaf(gx2, A.x, A.y);
            float dx3 = fmaf(gx3, A.x, A.y);
            float m0 = -(dx0 * dx0);
            float m1 = -(dx1 * dx1);
            float m2 = -(dx2 * dx2);
            float m3 = -(dx3 * dx3);
            float w00 = __builtin_amdgcn_exp2f(m0 + n0);
            float w01 = __builtin_amdgcn_exp2f(m1 + n0);
            float w02 = __builtin_amdgcn_exp2f(m2 + n0);
            float w03 = __builtin_amdgcn_exp2f(m3 + n0);
            float w10 = __builtin_amdgcn_exp2f(m0 + n1);
            float w11 = __builtin_amdgcn_exp2f(m1 + n1);
            float w12 = __builtin_amdgcn_exp2f(m2 + n1);
            float w13 = __builtin_amdgcn_exp2f(m3 + n1);
            r00 = fmaf(w00, cr, r00); g00 = fmaf(w00, cg, g00); b00 = fmaf(w00, cc, b00);
            r01 = fmaf(w01, cr, r01); g01 = fmaf(w01, cg, g01); b01 = fmaf(w01, cc, b01);
            r02 = fmaf(w02, cr, r02); g02 = fmaf(w02, cg, g02); b02 = fmaf(w02, cc, b02);
            r03 = fmaf(w03, cr, r03); g03 = fmaf(w03, cg, g03); b03 = fmaf(w03, cc, b03);
            r10 = fmaf(w10, cr, r10); g10 = fmaf(w10, cg, g10); b10 = fmaf(w10, cc, b10);
            r11 = fmaf(w11, cr, r11); g11 = fmaf(w11, cg, g11); b11 = fmaf(w11, cc, b11);
            r12 = fmaf(w12, cr, r12); g12 = fmaf(w12, cg, g12); b12 = fmaf(w12, cc, b12);
            r13 = fmaf(w13, cr, r13); g13 = fmaf(w13, cg, g13); b13 = fmaf(w13, cc, b13);
        }
    }

    // 2 rows x 12 consecutive floats -> 3 coalesced float4 stores per row
    size_t base0 = ((size_t)b * (HH * WW) + (size_t)h0 * WW + w0) * 3;
    float4* o0 = (float4*)(out + base0);
    float4* o1 = (float4*)(out + base0 + (size_t)WW * 3);
    o0[0] = make_float4(fminf(r00, 1.f), fminf(g00, 1.f), fminf(b00, 1.f), fminf(r01, 1.f));
    o0[1] = make_float4(fminf(g01, 1.f), fminf(b01, 1.f), fminf(r02, 1.f), fminf(g02, 1.f));
    o0[2] = make_float4(fminf(b02, 1.f), fminf(r03, 1.f), fminf(g03, 1.f), fminf(b03, 1.f));
    o1[0] = make_float4(fminf(r10, 1.f), fminf(g10, 1.f), fminf(b10, 1.f), fminf(r11, 1.f));
    o1[1] = make_float4(fminf(g11, 1.f), fminf(b11, 1.f), fminf(r12, 1.f), fminf(g12, 1.f));
    o1[2] = make_float4(fminf(b12, 1.f), fminf(r13, 1.f), fminf(g13, 1.f), fminf(b13, 1.f));
}

extern "C" void kernel_launch(void* const* d_in, const int* in_sizes, int n_in,
                              void* d_out, int out_size, void* d_ws, size_t ws_size,
                              hipStream_t stream) {
    const float* pos = (const float*)d_in[0];
    const float* col = (const float*)d_in[1];
    const float* siz = (const float*)d_in[2];
    float* out = (float*)d_out;
    splat_render<<<NBLK, TPB, 0, stream>>>(pos, col, siz, out);
}

// Round 5
// 77.356 us; speedup vs baseline: 1.0858x; 1.0858x over previous
//
#include <hip/hip_runtime.h>
#include <math.h>

#define HH 224
#define WW 224
#define NS 381                   // splats per image
#define BB 16                    // batch
#define TPB 256                  // 4 waves/block (occupancy: 3136 waves total)
#define TILE_W 32
#define TILE_H 32
#define TILES_X (WW / TILE_W)    // 7
#define BLKS_PER_IMG (TILES_X * (HH / TILE_H))  // 49
#define NBLK (BB * BLKS_PER_IMG)                // 784
#define NS_PAD 384
#define CUT 19.93f               // exp2 cutoff: weight < 2^-19.93 ~ 1e-6

// Fused kernel: per-tile cull+compact (constants computed on the fly from raw
// inputs) then render 4 px/thread (4 wide x 1 row).
// Splat record (ONE float4): {ss, -px*ss, -py*ss, rgb as 10:10:10 unorm},
// ss = sqrt(inv_two_var*log2e); weight = exp2(-((gx*ss-px*ss)^2+(gy*ss-py*ss)^2)).
// Color quant error <= 4.9e-4 * sum(w) ~ 1e-3 << 2e-2 threshold.
__global__ __launch_bounds__(TPB) void splat_render(const float* __restrict__ pos,
                                                    const float* __restrict__ col,
                                                    const float* __restrict__ siz,
                                                    float* __restrict__ out) {
    __shared__ float4 geo[NS_PAD];
    __shared__ int cnt;

    int blk = blockIdx.x;
    int b = blk / BLKS_PER_IMG;
    int t = blk - b * BLKS_PER_IMG;
    int tile_y = t / TILES_X;
    int tile_x = t - tile_y * TILES_X;

    if (threadIdx.x == 0) cnt = 0;
    __syncthreads();

    const float gstep = 2.0f / (float)(WW - 1);
    float x0 = -1.0f + (float)(tile_x * TILE_W) * gstep;
    float x1 = x0 + (float)(TILE_W - 1) * gstep;
    float y0 = -1.0f + (float)(tile_y * TILE_H) * gstep;
    float y1 = y0 + (float)(TILE_H - 1) * gstep;

    const float2* pb = (const float2*)(pos + (size_t)b * NS * 2);
    const float*  cb = col + (size_t)b * NS * 3;
    const float*  sb = siz + (size_t)b * NS;
    int lane = threadIdx.x & 63;

    // ---- cull + compact into LDS (2 rounds of 256) ----
    for (int r = 0; r < 2; ++r) {
        int i = threadIdx.x + r * TPB;
        bool pass = false;
        float4 A = make_float4(0.f, 0.f, 0.f, 0.f);
        if (i < NS) {
            float2 p = pb[i];
            float sg = sb[i] * (2.0f / (float)HH);
            float itv = 1.0f / (2.0f * sg * sg + 1e-8f);
            float ss = sqrtf(itv * 1.44269504088896340736f);
            float u = p.x * ss, v = p.y * ss;
            float dxm = fmaxf(fmaxf(x0 * ss - u, u - x1 * ss), 0.0f);
            float dym = fmaxf(fmaxf(y0 * ss - v, v - y1 * ss), 0.0f);
            pass = fmaf(dxm, dxm, dym * dym) < CUT;   // min scaled dist^2 to tile rect
            if (pass) {
                unsigned pr = (unsigned)fmaf(cb[3 * i + 0], 1023.0f, 0.5f);
                unsigned pg = (unsigned)fmaf(cb[3 * i + 1], 1023.0f, 0.5f);
                unsigned pc = (unsigned)fmaf(cb[3 * i + 2], 1023.0f, 0.5f);
                A = make_float4(ss, -u, -v, __uint_as_float(pr | (pg << 10) | (pc << 20)));
            }
        }
        unsigned long long mask = __ballot(pass);
        int ofs = __popcll(mask & ((1ull << lane) - 1ull));
        int tot = __popcll(mask);
        int base = 0;
        if (lane == 0 && tot) base = atomicAdd(&cnt, tot);
        base = __shfl(base, 0);
        if (pass) geo[base + ofs] = A;
    }
    __syncthreads();
    int m = cnt;
    int m4 = (m + 3) & ~3;      // pad to multiple of 4 with always-fail dummies
    if (threadIdx.x < (m4 - m))
        geo[m + threadIdx.x] = make_float4(0.f, 0.f, 1000.0f, 0.f);
    __syncthreads();
    m4 = __builtin_amdgcn_readfirstlane(m4);

    // ---- render 4 px/thread (one row of 4) ----
    int tx = threadIdx.x & 7;           // 8 x-groups * 4 px = 32 px
    int ty = threadIdx.x >> 3;          // 32 rows
    int w0 = tile_x * TILE_W + tx * 4;
    int h  = tile_y * TILE_H + ty;
    float gy  = -1.0f + (float)h * gstep;
    float gx0 = -1.0f + (float)w0 * gstep;
    float gx1 = gx0 + gstep;
    float gx2 = gx0 + 2.0f * gstep;
    float gx3 = gx0 + 3.0f * gstep;

    float r0 = 0.f, g0 = 0.f, b0 = 0.f;
    float r1 = 0.f, g1 = 0.f, b1 = 0.f;
    float r2 = 0.f, g2 = 0.f, b2 = 0.f;
    float r3 = 0.f, g3 = 0.f, b3 = 0.f;

#pragma unroll 4
    for (int j = 0; j < m4; ++j) {
        float4 A = geo[j];              // broadcast ds_read_b128
        float dy  = fmaf(gy, A.x, A.z);
        float ndd = -(dy * dy);         // weight <= exp2(ndd)
        if (ndd > -CUT) {
            unsigned pk = __float_as_uint(A.w);
            const float q = (1.0f / 1023.0f);
            float cr = (float)(pk & 1023u) * q;
            float cg = (float)((pk >> 10) & 1023u) * q;
            float cc = (float)(pk >> 20) * q;
            float dx0 = fmaf(gx0, A.x, A.y);
            float dx1 = fmaf(gx1, A.x, A.y);
            float dx2 = fmaf(gx2, A.x, A.y);
            float dx3 = fmaf(gx3, A.x, A.y);
            float we0 = __builtin_amdgcn_exp2f(fmaf(-dx0, dx0, ndd));
            float we1 = __builtin_amdgcn_exp2f(fmaf(-dx1, dx1, ndd));
            float we2 = __builtin_amdgcn_exp2f(fmaf(-dx2, dx2, ndd));
            float we3 = __builtin_amdgcn_exp2f(fmaf(-dx3, dx3, ndd));
            r0 = fmaf(we0, cr, r0); g0 = fmaf(we0, cg, g0); b0 = fmaf(we0, cc, b0);
            r1 = fmaf(we1, cr, r1); g1 = fmaf(we1, cg, g1); b1 = fmaf(we1, cc, b1);
            r2 = fmaf(we2, cr, r2); g2 = fmaf(we2, cg, g2); b2 = fmaf(we2, cc, b2);
            r3 = fmaf(we3, cr, r3); g3 = fmaf(we3, cg, g3); b3 = fmaf(we3, cc, b3);
        }
    }

    // 12 consecutive floats -> 3 coalesced float4 stores
    float4* o4 = (float4*)(out + ((size_t)b * (HH * WW) + (size_t)h * WW + w0) * 3);
    o4[0] = make_float4(fminf(r0, 1.f), fminf(g0, 1.f), fminf(b0, 1.f), fminf(r1, 1.f));
    o4[1] = make_float4(fminf(g1, 1.f), fminf(b1, 1.f), fminf(r2, 1.f), fminf(g2, 1.f));
    o4[2] = make_float4(fminf(b2, 1.f), fminf(r3, 1.f), fminf(g3, 1.f), fminf(b3, 1.f));
}

extern "C" void kernel_launch(void* const* d_in, const int* in_sizes, int n_in,
                              void* d_out, int out_size, void* d_ws, size_t ws_size,
                              hipStream_t stream) {
    const float* pos = (const float*)d_in[0];
    const float* col = (const float*)d_in[1];
    const float* siz = (const float*)d_in[2];
    float* out = (float*)d_out;
    splat_render<<<NBLK, TPB, 0, stream>>>(pos, col, siz, out);
}